// Round 2
// baseline (820.757 us; speedup 1.0000x reference)
//
#include <hip/hip_runtime.h>
#include <hip/hip_cooperative_groups.h>

namespace cg = cooperative_groups;

// S4 layer, MI355X. B=16, T=2048, H=1024, N=64.
// SINGLE cooperative kernel, 256 blocks x 512 threads (1 block/CU), phases split
// by grid.sync():
//   A0 : B_bar=B*exp(ldt)->bf16, C->bf16 (16K threads)  ||  Taylor expm prep (2 waves)
//   A1 : u = x @ B_bar^T   (2048 waves, LDS-free reg-fragment MFMA, 16 bt rows/wave)
//   B  : scan_local  - 32 chunks x 64 steps -> F_c        (blocks 0..31, wave 0)
//   C  : scan_chunks - 32-step boundary scan with A_L -> P_c   (block 0, wave 0)
//   D  : scan_final  - re-run chunks from P_c, states bf16 (T,B,N)
//   E  : out = states @ C^T + D*x  (2048 waves, A-frags hoisted, LDS-free)
// ws map (floats): [0]A_bar(4096) [4096]A_L(4096)
//                  [8192]F(32768)  <-- ALIASED by Bbf bf16 (A0->A1, dead before B writes F)
//                  [40960]P(32768) [73728]u(2097152, layout (T,B,N) fp32)
//                  [2170880]states bf16 (lower half) [3219456]Cbf bf16

#define H   1024
#define TT  2048
#define LCH 64
#define KCH 32

typedef __attribute__((ext_vector_type(8))) short bf16x8;
typedef __attribute__((ext_vector_type(4))) float f32x4;
typedef __attribute__((ext_vector_type(2))) unsigned int u32x2;

#define WS_ABAR 0
#define WS_AL   4096
#define WS_F    8192
#define WS_P    40960
#define WS_U    73728
#define WS_S    2170880
#define WS_BBF  8192      // aliases F: written A0, read A1, dead before phase B writes F
#define WS_CBF  3219456   // upper half of states region (states bf16 need lower half only)

__device__ __forceinline__ unsigned short f2bf(float x) {
  union { float f; unsigned u; } v; v.f = x;
  unsigned r = (v.u + 0x7FFFu + ((v.u >> 16) & 1u)) >> 16;   // RNE
  return (unsigned short)r;
}

__device__ __forceinline__ bf16x8 packbf8(f32x4 a, f32x4 b) {
  bf16x8 r;
  r[0] = (short)f2bf(a[0]); r[1] = (short)f2bf(a[1]);
  r[2] = (short)f2bf(a[2]); r[3] = (short)f2bf(a[3]);
  r[4] = (short)f2bf(b[0]); r[5] = (short)f2bf(b[1]);
  r[6] = (short)f2bf(b[2]); r[7] = (short)f2bf(b[3]);
  return r;
}

__device__ __forceinline__ u32x2 packbf4(f32x4 v) {
  u32x2 r;
  r[0] = (unsigned)f2bf(v[0]) | ((unsigned)f2bf(v[1]) << 16);
  r[1] = (unsigned)f2bf(v[2]) | ((unsigned)f2bf(v[3]) << 16);
  return r;
}

__device__ __forceinline__ f32x4 mfma16(bf16x8 a, bf16x8 b, f32x4 c) {
  // D[m][n]=sum_k A[m][k]*B[k][n]+C. A: lane m=lane&15,k=(lane>>4)*8+j;
  // B: k=(lane>>4)*8+j,n=lane&15; C/D: col=lane&15,row=(lane>>4)*4+reg.
  return __builtin_amdgcn_mfma_f32_16x16x32_bf16(a, b, c, 0, 0, 0);
}

// ---------------- prep: E = expm(scale*A), 1 wave, Taylor-12 via bf16 MFMA ----------------
__device__ void prep_block(const float* Ain, const float* ldt, float* ws, int which) {
  __shared__ float Mb[64 * 68];   // Mb[n][k] = M[k][n]  (B-operand view, +pad)
  __shared__ short Tl[64 * 72];   // current term, A-layout [m][k] bf16 (+pad)
  const int lane = threadIdx.x;
  const int cq = lane >> 4, cl = lane & 15;

  float s = 0.f;
  for (int j = 0; j < 16; ++j) s += expf(ldt[lane + j * 64]);
  for (int off = 32; off; off >>= 1) s += __shfl_down(s, off);
  float dtm = __shfl(s, 0) * (1.0f / 1024.0f);
  float scale = which ? dtm * (float)LCH : dtm;

  for (int idx = lane; idx < 4096; idx += 64) {
    int r = idx >> 6, c = idx & 63;
    float v = Ain[idx] * scale;
    Mb[c * 68 + r] = v;
    Tl[r * 72 + c] = (short)f2bf(v);       // term1 = M
  }

  float E[16][4];                           // C/D-layout accumulator, fp32
  for (int mt = 0; mt < 4; ++mt)
    for (int nt = 0; nt < 4; ++nt)
      for (int r = 0; r < 4; ++r) {
        int row = mt * 16 + cq * 4 + r, col = nt * 16 + cl;
        E[mt * 4 + nt][r] = (row == col ? 1.f : 0.f) + Ain[row * 64 + col] * scale;
      }

  __asm volatile("s_waitcnt lgkmcnt(0)" ::: "memory");

  for (int it = 2; it <= 12; ++it) {
    bf16x8 af[4][2];
    for (int mt = 0; mt < 4; ++mt)
      for (int kh = 0; kh < 2; ++kh)
        af[mt][kh] = *(const bf16x8*)&Tl[(mt * 16 + cl) * 72 + kh * 32 + cq * 8];
    float inv = 1.0f / (float)it;
    bf16x8 bfr[4][2];
    for (int nt = 0; nt < 4; ++nt)
      for (int kh = 0; kh < 2; ++kh) {
        const float* p = &Mb[(nt * 16 + cl) * 68 + kh * 32 + cq * 8];
        f32x4 a = *(const f32x4*)p;
        f32x4 b = *(const f32x4*)(p + 4);
        bfr[nt][kh] = packbf8(a * inv, b * inv);
      }
    f32x4 zero = {0.f, 0.f, 0.f, 0.f};
    f32x4 acc[16];
    for (int i = 0; i < 16; ++i) acc[i] = zero;
    for (int mt = 0; mt < 4; ++mt)
      for (int nt = 0; nt < 4; ++nt) {
        acc[mt * 4 + nt] = mfma16(af[mt][0], bfr[nt][0], acc[mt * 4 + nt]);
        acc[mt * 4 + nt] = mfma16(af[mt][1], bfr[nt][1], acc[mt * 4 + nt]);
      }
    __asm volatile("s_waitcnt lgkmcnt(0)" ::: "memory");
    for (int mt = 0; mt < 4; ++mt)
      for (int nt = 0; nt < 4; ++nt)
        for (int r = 0; r < 4; ++r) {
          float t = acc[mt * 4 + nt][r];
          E[mt * 4 + nt][r] += t;
          Tl[(mt * 16 + cq * 4 + r) * 72 + nt * 16 + cl] = (short)f2bf(t);
        }
    __asm volatile("s_waitcnt lgkmcnt(0)" ::: "memory");
  }

  float* dst = ws + (which ? WS_AL : WS_ABAR);
  for (int mt = 0; mt < 4; ++mt)
    for (int nt = 0; nt < 4; ++nt)
      for (int r = 0; r < 4; ++r)
        dst[(mt * 16 + cq * 4 + r) * 64 + nt * 16 + cl] = E[mt * 4 + nt][r];
}

// ---------------- u = x @ B_bar^T : one wave = 16 bt rows, LDS-free ----------------
__device__ void gemm_u_wave(const float* x, const float* ws, float* u2, int w) {
  const short* Bbf = (const short*)(ws + WS_BBF);
  const int lane = threadIdx.x & 63;
  const int cq = lane >> 4, cl = lane & 15;
  const int bt0 = w * 16;

  const float* xr = x + (long)(bt0 + cl) * H + cq * 8;   // A rows: m = cl
  const short* br = Bbf + cq * 8;

  f32x4 zero = {0.f, 0.f, 0.f, 0.f};
  f32x4 acc[4];
  for (int i = 0; i < 4; ++i) acc[i] = zero;

#pragma unroll 4
  for (int ks = 0; ks < 32; ++ks) {
    const int k0 = ks * 32;
    f32x4 xa = *(const f32x4*)(xr + k0);
    f32x4 xb = *(const f32x4*)(xr + k0 + 4);
    bf16x8 af = packbf8(xa, xb);
    for (int nt = 0; nt < 4; ++nt) {
      bf16x8 bf = *(const bf16x8*)(br + (nt * 16 + cl) * H + k0);   // B: n = cl
      acc[nt] = mfma16(af, bf, acc[nt]);
    }
  }

  for (int nt = 0; nt < 4; ++nt)
    for (int r = 0; r < 4; ++r) {
      int obt = bt0 + cq * 4 + r;                 // C/D rows: m = cq*4+r
      int t = obt & (TT - 1), b = obt >> 11;
      u2[(long)(t * 16 + b) * 64 + nt * 16 + cl] = acc[nt][r];
    }
}

// ---------------- scan step: Z_new = (I+R) @ Z + U, transposed (Z is N x B) ----------------
__device__ __forceinline__ void load_RF(const float* Amat, bf16x8 Rf[4][2], int cq, int cl) {
  for (int mt = 0; mt < 4; ++mt)
    for (int kh = 0; kh < 2; ++kh) {
      int m = mt * 16 + cl;
      int kb = kh * 32 + cq * 8;
      f32x4 v0 = *(const f32x4*)&Amat[m * 64 + kb];
      f32x4 v1 = *(const f32x4*)&Amat[m * 64 + kb + 4];
      for (int j = 0; j < 4; ++j) {
        if (m == kb + j) v0[j] -= 1.f;          // R = A_bar - I
        if (m == kb + 4 + j) v1[j] -= 1.f;
      }
      Rf[mt][kh] = packbf8(v0, v1);
    }
}

// Single wave. Z[4] f32x4 in C/D layout: per lane state i = tile*16+cq*4+reg, batch b=cl.
__device__ __forceinline__ void scan_step(f32x4 Z[4], const bf16x8 Rf[4][2], short* Zl,
                                          const f32x4 U[4], int cq, int cl) {
  for (int t = 0; t < 4; ++t)
    *(u32x2*)&Zl[cl * 72 + t * 16 + cq * 4] = packbf4(Z[t]);   // old Z -> bf16 LDS
  __asm volatile("s_waitcnt lgkmcnt(0)" ::: "memory");
  bf16x8 zf0 = *(const bf16x8*)&Zl[cl * 72 + cq * 8];
  bf16x8 zf1 = *(const bf16x8*)&Zl[cl * 72 + 32 + cq * 8];
  for (int t = 0; t < 4; ++t) Z[t] += U[t];                    // identity path + input, fp32
  for (int mt = 0; mt < 4; ++mt) {
    Z[mt] = mfma16(Rf[mt][0], zf0, Z[mt]);                     // += R @ Z_old
    Z[mt] = mfma16(Rf[mt][1], zf1, Z[mt]);
  }
}

__device__ void scan_local_d(float* ws, int c) {
  const float* Abar = ws + WS_ABAR;
  const float* u2 = ws + WS_U;
  float* F = ws + WS_F;
  __shared__ short Zl_b[16 * 72];
  const int lane = threadIdx.x & 63, cq = lane >> 4, cl = lane & 15;
  bf16x8 Rf[4][2];
  load_RF(Abar, Rf, cq, cl);
  f32x4 zero = {0.f, 0.f, 0.f, 0.f};
  f32x4 Z[4], U[4], Un[4];
  for (int t = 0; t < 4; ++t) Z[t] = zero;
  const float* ub = u2 + (long)c * LCH * 1024 + cl * 64 + cq * 4;
  for (int t = 0; t < 4; ++t) U[t] = *(const f32x4*)(ub + t * 16);
  for (int ti = 0; ti < LCH; ++ti) {
    const float* un = ub + (ti + 1) * 1024;   // prefetch (last iter reads scratch: harmless)
    for (int t = 0; t < 4; ++t) Un[t] = *(const f32x4*)(un + t * 16);
    scan_step(Z, Rf, Zl_b, U, cq, cl);
    for (int t = 0; t < 4; ++t) U[t] = Un[t];
  }
  for (int t = 0; t < 4; ++t)
    *(f32x4*)&F[(long)c * 1024 + cl * 64 + t * 16 + cq * 4] = Z[t];
}

__device__ void scan_chunks_d(float* ws) {
  const float* AL = ws + WS_AL;
  const float* F = ws + WS_F;
  float* P = ws + WS_P;
  __shared__ short Zl_c[16 * 72];
  const int lane = threadIdx.x & 63, cq = lane >> 4, cl = lane & 15;
  bf16x8 Rf[4][2];
  load_RF(AL, Rf, cq, cl);
  f32x4 zero = {0.f, 0.f, 0.f, 0.f};
  f32x4 Z[4], U[4];
  for (int t = 0; t < 4; ++t) Z[t] = zero;
  for (int c = 0; c < KCH; ++c) {
    long off = (long)c * 1024 + cl * 64 + cq * 4;
    for (int t = 0; t < 4; ++t) *(f32x4*)&P[off + t * 16] = Z[t];   // P_c before update
    for (int t = 0; t < 4; ++t) U[t] = *(const f32x4*)&F[off + t * 16];
    scan_step(Z, Rf, Zl_c, U, cq, cl);                               // P_{c+1} = A_L P_c + F_c
  }
}

__device__ void scan_final_d(float* ws, int c) {
  const float* Abar = ws + WS_ABAR;
  const float* u2 = ws + WS_U;
  const float* P = ws + WS_P;
  short* S2bf = (short*)(ws + WS_S);
  __shared__ short Zl_f[16 * 72];
  const int lane = threadIdx.x & 63, cq = lane >> 4, cl = lane & 15;
  bf16x8 Rf[4][2];
  load_RF(Abar, Rf, cq, cl);
  f32x4 Z[4], U[4], Un[4];
  long poff = (long)c * 1024 + cl * 64 + cq * 4;
  for (int t = 0; t < 4; ++t) Z[t] = *(const f32x4*)&P[poff + t * 16];
  const float* ub = u2 + (long)c * LCH * 1024 + cl * 64 + cq * 4;
  short* sb = S2bf + (long)c * LCH * 1024 + cl * 64 + cq * 4;
  for (int t = 0; t < 4; ++t) U[t] = *(const f32x4*)(ub + t * 16);
  for (int ti = 0; ti < LCH; ++ti) {
    const float* un = ub + (ti + 1) * 1024;
    for (int t = 0; t < 4; ++t) Un[t] = *(const f32x4*)(un + t * 16);
    scan_step(Z, Rf, Zl_f, U, cq, cl);
    short* so = sb + ti * 1024;
    for (int t = 0; t < 4; ++t) *(u32x2*)(so + t * 16) = packbf4(Z[t]);  // states bf16
    for (int t = 0; t < 4; ++t) U[t] = Un[t];
  }
}

// ---------------- out = states @ C^T + D*x : one wave = 16 bt rows x all H ----------------
__device__ void out_wave(const float* ws, const float* Dv, const float* x, float* out, int w) {
  const short* Sbf = (const short*)(ws + WS_S);
  const short* Cbf = (const short*)(ws + WS_CBF);
  const int lane = threadIdx.x & 63;
  const int cq = lane >> 4, cl = lane & 15;
  const int bt0 = w * 16;

  const int abt = bt0 + cl;                      // A rows: m = cl
  const int at = abt & (TT - 1), ab = abt >> 11;
  const short* sr = Sbf + (long)(at * 16 + ab) * 64 + cq * 8;
  bf16x8 a0 = *(const bf16x8*)(sr);              // states frags hoisted (reused for all h)
  bf16x8 a1 = *(const bf16x8*)(sr + 32);

  for (int hb = 0; hb < 8; ++hb) {
#pragma unroll
    for (int nt = 0; nt < 8; ++nt) {
      const int h = hb * 128 + nt * 16 + cl;     // B: n = cl -> h
      const short* cr = Cbf + (long)h * 64 + cq * 8;
      bf16x8 b0 = *(const bf16x8*)(cr);
      bf16x8 b1 = *(const bf16x8*)(cr + 32);
      f32x4 acc = {0.f, 0.f, 0.f, 0.f};
      acc = mfma16(a0, b0, acc);
      acc = mfma16(a1, b1, acc);
      const float d = Dv[h];
      for (int r = 0; r < 4; ++r) {
        long obt = bt0 + cq * 4 + r;             // C/D rows: m = cq*4+r
        long idx = obt * H + h;
        out[idx] = acc[r] + d * x[idx];          // x-path kept fp32
      }
    }
  }
}

// ---------------- the single cooperative kernel ----------------
__global__ __launch_bounds__(512, 2) void fused_k(const float* x, const float* Ain,
                                                  const float* Bm, const float* Cm,
                                                  const float* Dv, const float* ldt,
                                                  float* out, float* ws) {
  cg::grid_group grid = cg::this_grid();
  const int bid = blockIdx.x, tid = threadIdx.x;
  const int wid = tid >> 6;
  const int w = bid * 8 + wid;                   // global wave id, 0..2047

  // ---- A0: bf16 precompute of B_bar / C  ||  Taylor expm prep (2 waves) ----
  {
    const int tg = bid * 512 + tid;
    if (tg < 16384) {
      short* Bbf = (short*)(ws + WS_BBF);   // Bbf[n][h] = bf16(B[n][h]*exp(ldt[h]))
      short* Cbf = (short*)(ws + WS_CBF);   // Cbf[h][n] = bf16(C[h][n])
      const int idx = tg * 4;
      f32x4 b = *(const f32x4*)(Bm + idx);
      f32x4 l = *(const f32x4*)(ldt + (idx & (H - 1)));
      f32x4 bb;
      for (int j = 0; j < 4; ++j) bb[j] = b[j] * expf(l[j]);
      *(u32x2*)&Bbf[idx] = packbf4(bb);
      f32x4 c = *(const f32x4*)(Cm + idx);
      *(u32x2*)&Cbf[idx] = packbf4(c);
    }
    if (bid < 2 && wid == 0) prep_block(Ain, ldt, ws, bid);
  }
  __threadfence();
  grid.sync();

  // ---- A1: u = x @ B_bar^T ----
  gemm_u_wave(x, ws, ws + WS_U, w);
  __threadfence();
  grid.sync();

  // ---- B: local scans ----
  if (bid < KCH && wid == 0) scan_local_d(ws, bid);
  __threadfence();
  grid.sync();

  // ---- C: boundary scan ----
  if (bid == 0 && wid == 0) scan_chunks_d(ws);
  __threadfence();
  grid.sync();

  // ---- D: final scans, write states ----
  if (bid < KCH && wid == 0) scan_final_d(ws, bid);
  __threadfence();
  grid.sync();

  // ---- E: out = states @ C^T + D*x ----
  out_wave(ws, Dv, x, out, w);
}

extern "C" void kernel_launch(void* const* d_in, const int* in_sizes, int n_in,
                              void* d_out, int out_size, void* d_ws, size_t ws_size,
                              hipStream_t stream) {
  const float* x = (const float*)d_in[0];
  const float* A = (const float*)d_in[1];
  const float* Bm = (const float*)d_in[2];
  const float* Cm = (const float*)d_in[3];
  const float* Dv = (const float*)d_in[4];
  const float* ldt = (const float*)d_in[5];
  float* out = (float*)d_out;
  float* ws = (float*)d_ws;

  void* args[] = {(void*)&x, (void*)&A, (void*)&Bm, (void*)&Cm,
                  (void*)&Dv, (void*)&ldt, (void*)&out, (void*)&ws};
  hipLaunchCooperativeKernel((void*)fused_k, dim3(256), dim3(512), args, 0, stream);
}

// Round 3
// 490.930 us; speedup vs baseline: 1.6718x; 1.6718x over previous
//
#include <hip/hip_runtime.h>

// S4 layer, MI355X. B=16, T=2048, H=1024, N=64.
// Split-kernel pipeline (coop-fusion regressed 507->820 in R2; reverted):
//   k0          : blocks 0..63  B_bar=B*exp(ldt)->bf16, C->bf16
//                 blocks 64,65  Taylor expm(M)/expm(64*M) (1 wave each, bf16 MFMA)
//   k1          : u^T = B_bar @ x^T  (operand-swapped MFMA -> 16B/lane u stores,
//                 2-deep x prefetch; LDS-free)
//   scan_local  : 32 chunks x 64 steps, zero-init local scans -> F_c (I+R MFMA step)
//   scan_final  : block c redoes <=31 boundary steps with A_L (replaces scan_chunks
//                 kernel; bitwise-same chain), then 64-step final scan, states bf16
//   out_proj    : out^T tiles = C @ states^T  (operand-swapped -> 16B/lane x-read &
//                 out-write, states frag hoisted; LDS-free) + D*x
// ws map (floats): [0]A_bar(4096) [4096]A_L(4096)
//                  [8192]F(32768)  <-- ALIASED by Bbf bf16 (k0->k1, dead before scan_local)
//                  [40960]P(unused now) [73728]u(2097152, layout (T,B,N) fp32)
//                  [2170880]states bf16 (4MB) [3219456]Cbf bf16

#define H   1024
#define TT  2048
#define LCH 64
#define KCH 32

typedef __attribute__((ext_vector_type(8))) short bf16x8;
typedef __attribute__((ext_vector_type(4))) float f32x4;
typedef __attribute__((ext_vector_type(2))) unsigned int u32x2;

#define WS_ABAR 0
#define WS_AL   4096
#define WS_F    8192
#define WS_P    40960
#define WS_U    73728
#define WS_S    2170880
#define WS_BBF  8192      // aliases F: written k0, read k1, dead before scan_local writes F
#define WS_CBF  3219456   // after states-bf16 region

__device__ __forceinline__ unsigned short f2bf(float x) {
  union { float f; unsigned u; } v; v.f = x;
  unsigned r = (v.u + 0x7FFFu + ((v.u >> 16) & 1u)) >> 16;   // RNE
  return (unsigned short)r;
}

__device__ __forceinline__ bf16x8 packbf8(f32x4 a, f32x4 b) {
  bf16x8 r;
  r[0] = (short)f2bf(a[0]); r[1] = (short)f2bf(a[1]);
  r[2] = (short)f2bf(a[2]); r[3] = (short)f2bf(a[3]);
  r[4] = (short)f2bf(b[0]); r[5] = (short)f2bf(b[1]);
  r[6] = (short)f2bf(b[2]); r[7] = (short)f2bf(b[3]);
  return r;
}

__device__ __forceinline__ u32x2 packbf4(f32x4 v) {
  u32x2 r;
  r[0] = (unsigned)f2bf(v[0]) | ((unsigned)f2bf(v[1]) << 16);
  r[1] = (unsigned)f2bf(v[2]) | ((unsigned)f2bf(v[3]) << 16);
  return r;
}

__device__ __forceinline__ f32x4 mfma16(bf16x8 a, bf16x8 b, f32x4 c) {
  // D[m][n]=sum_k A[m][k]*B[k][n]+C. A: lane m=lane&15,k=(lane>>4)*8+j;
  // B: k=(lane>>4)*8+j,n=lane&15; C/D: col=lane&15,row=(lane>>4)*4+reg.
  return __builtin_amdgcn_mfma_f32_16x16x32_bf16(a, b, c, 0, 0, 0);
}

// ---------------- prep: E = expm(scale*A), 1 wave, Taylor-12 via bf16 MFMA ----------------
__device__ void prep_block(const float* Ain, const float* ldt, float* ws, int which) {
  __shared__ float Mb[64 * 68];   // Mb[n][k] = M[k][n]  (B-operand view, +pad)
  __shared__ short Tl[64 * 72];   // current term, A-layout [m][k] bf16 (+pad)
  const int lane = threadIdx.x;
  const int cq = lane >> 4, cl = lane & 15;

  float s = 0.f;
  for (int j = 0; j < 16; ++j) s += expf(ldt[lane + j * 64]);
  for (int off = 32; off; off >>= 1) s += __shfl_down(s, off);
  float dtm = __shfl(s, 0) * (1.0f / 1024.0f);
  float scale = which ? dtm * (float)LCH : dtm;

  for (int idx = lane; idx < 4096; idx += 64) {
    int r = idx >> 6, c = idx & 63;
    float v = Ain[idx] * scale;
    Mb[c * 68 + r] = v;
    Tl[r * 72 + c] = (short)f2bf(v);       // term1 = M
  }

  float E[16][4];                           // C/D-layout accumulator, fp32
  for (int mt = 0; mt < 4; ++mt)
    for (int nt = 0; nt < 4; ++nt)
      for (int r = 0; r < 4; ++r) {
        int row = mt * 16 + cq * 4 + r, col = nt * 16 + cl;
        E[mt * 4 + nt][r] = (row == col ? 1.f : 0.f) + Ain[row * 64 + col] * scale;
      }

  __asm volatile("s_waitcnt lgkmcnt(0)" ::: "memory");

  for (int it = 2; it <= 12; ++it) {
    bf16x8 af[4][2];
    for (int mt = 0; mt < 4; ++mt)
      for (int kh = 0; kh < 2; ++kh)
        af[mt][kh] = *(const bf16x8*)&Tl[(mt * 16 + cl) * 72 + kh * 32 + cq * 8];
    float inv = 1.0f / (float)it;
    bf16x8 bfr[4][2];
    for (int nt = 0; nt < 4; ++nt)
      for (int kh = 0; kh < 2; ++kh) {
        const float* p = &Mb[(nt * 16 + cl) * 68 + kh * 32 + cq * 8];
        f32x4 a = *(const f32x4*)p;
        f32x4 b = *(const f32x4*)(p + 4);
        bfr[nt][kh] = packbf8(a * inv, b * inv);
      }
    f32x4 zero = {0.f, 0.f, 0.f, 0.f};
    f32x4 acc[16];
    for (int i = 0; i < 16; ++i) acc[i] = zero;
    for (int mt = 0; mt < 4; ++mt)
      for (int nt = 0; nt < 4; ++nt) {
        acc[mt * 4 + nt] = mfma16(af[mt][0], bfr[nt][0], acc[mt * 4 + nt]);
        acc[mt * 4 + nt] = mfma16(af[mt][1], bfr[nt][1], acc[mt * 4 + nt]);
      }
    __asm volatile("s_waitcnt lgkmcnt(0)" ::: "memory");
    for (int mt = 0; mt < 4; ++mt)
      for (int nt = 0; nt < 4; ++nt)
        for (int r = 0; r < 4; ++r) {
          float t = acc[mt * 4 + nt][r];
          E[mt * 4 + nt][r] += t;
          Tl[(mt * 16 + cq * 4 + r) * 72 + nt * 16 + cl] = (short)f2bf(t);
        }
    __asm volatile("s_waitcnt lgkmcnt(0)" ::: "memory");
  }

  float* dst = ws + (which ? WS_AL : WS_ABAR);
  for (int mt = 0; mt < 4; ++mt)
    for (int nt = 0; nt < 4; ++nt)
      for (int r = 0; r < 4; ++r)
        dst[(mt * 16 + cq * 4 + r) * 64 + nt * 16 + cl] = E[mt * 4 + nt][r];
}

// ---------------- k0: bf16 precompute of B_bar / C  +  expm preps ----------------
__global__ __launch_bounds__(256) void k0(const float* Bm, const float* Cm,
                                          const float* Ain, const float* ldt, float* ws) {
  if (blockIdx.x >= 64) {
    if (threadIdx.x < 64) prep_block(Ain, ldt, ws, blockIdx.x - 64);
    return;
  }
  short* Bbf = (short*)(ws + WS_BBF);   // Bbf[n][h] = bf16(B[n][h]*exp(ldt[h]))
  short* Cbf = (short*)(ws + WS_CBF);   // Cbf[h][n] = bf16(C[h][n])
  const int idx = (blockIdx.x * 256 + threadIdx.x) * 4;   // 64 blocks -> 65536 elems
  f32x4 b = *(const f32x4*)(Bm + idx);
  f32x4 l = *(const f32x4*)(ldt + (idx & (H - 1)));
  f32x4 bb;
  for (int j = 0; j < 4; ++j) bb[j] = b[j] * expf(l[j]);
  *(u32x2*)&Bbf[idx] = packbf4(bb);
  f32x4 c = *(const f32x4*)(Cm + idx);
  *(u32x2*)&Cbf[idx] = packbf4(c);
}

// ---------------- k1: u^T-tiles = B_bar @ x^T (operand-swapped, LDS-free) --------------
// Wave w owns bt rows [w*16, w*16+16). Loads identical to the un-swapped version;
// D-layout now gives each lane 4 CONSECUTIVE n-states -> 16B u stores.
__global__ __launch_bounds__(256) void k1(const float* x, float* ws) {
  const short* Bbf = (const short*)(ws + WS_BBF);
  float* u2 = ws + WS_U;
  const int tid = threadIdx.x;
  const int wid = tid >> 6, lane = tid & 63;
  const int cq = lane >> 4, cl = lane & 15;
  const int bt0 = (blockIdx.x * 4 + wid) * 16;

  const float* xr = x + (long)(bt0 + cl) * H + cq * 8;   // B-operand: n = cl (bt row)
  const short* br = Bbf + cq * 8;                        // A-operand: m = cl (state row)

  f32x4 zero = {0.f, 0.f, 0.f, 0.f};
  f32x4 acc[4];
  for (int i = 0; i < 4; ++i) acc[i] = zero;

  f32x4 pxa[2], pxb[2];                                  // 2-deep x prefetch pipeline
  pxa[0] = *(const f32x4*)(xr);       pxb[0] = *(const f32x4*)(xr + 4);
  pxa[1] = *(const f32x4*)(xr + 32);  pxb[1] = *(const f32x4*)(xr + 36);

#pragma unroll
  for (int ks = 0; ks < 32; ++ks) {
    f32x4 xa = pxa[ks & 1], xb = pxb[ks & 1];
    if (ks < 30) {
      pxa[ks & 1] = *(const f32x4*)(xr + (ks + 2) * 32);
      pxb[ks & 1] = *(const f32x4*)(xr + (ks + 2) * 32 + 4);
    }
    bf16x8 bfx = packbf8(xa, xb);
#pragma unroll
    for (int nt = 0; nt < 4; ++nt) {
      bf16x8 bfb = *(const bf16x8*)(br + (nt * 16 + cl) * H + ks * 32);
      acc[nt] = mfma16(bfb, bfx, acc[nt]);               // swapped: D[m=state][n=bt]
    }
  }

  const int bt = bt0 + cl;
  const int t = bt & (TT - 1), b = bt >> 11;
  float* ur = u2 + (long)(t * 16 + b) * 64 + cq * 4;
#pragma unroll
  for (int nt = 0; nt < 4; ++nt)
    *(f32x4*)(ur + nt * 16) = acc[nt];                   // 4 consecutive n per lane
}

// ---------------- scan step: Z_new = (I+R) @ Z + U, transposed (Z is N x B) ----------------
__device__ __forceinline__ void load_RF(const float* Amat, bf16x8 Rf[4][2], int cq, int cl) {
  for (int mt = 0; mt < 4; ++mt)
    for (int kh = 0; kh < 2; ++kh) {
      int m = mt * 16 + cl;
      int kb = kh * 32 + cq * 8;
      f32x4 v0 = *(const f32x4*)&Amat[m * 64 + kb];
      f32x4 v1 = *(const f32x4*)&Amat[m * 64 + kb + 4];
      for (int j = 0; j < 4; ++j) {
        if (m == kb + j) v0[j] -= 1.f;          // R = A_bar - I
        if (m == kb + 4 + j) v1[j] -= 1.f;
      }
      Rf[mt][kh] = packbf8(v0, v1);
    }
}

// Single wave. Z[4] f32x4 in C/D layout: per lane state i = tile*16+cq*4+reg, batch b=cl.
__device__ __forceinline__ void scan_step(f32x4 Z[4], const bf16x8 Rf[4][2], short* Zl,
                                          const f32x4 U[4], int cq, int cl) {
  for (int t = 0; t < 4; ++t)
    *(u32x2*)&Zl[cl * 72 + t * 16 + cq * 4] = packbf4(Z[t]);   // old Z -> bf16 LDS
  __asm volatile("s_waitcnt lgkmcnt(0)" ::: "memory");
  bf16x8 zf0 = *(const bf16x8*)&Zl[cl * 72 + cq * 8];
  bf16x8 zf1 = *(const bf16x8*)&Zl[cl * 72 + 32 + cq * 8];
  for (int t = 0; t < 4; ++t) Z[t] += U[t];                    // identity path + input, fp32
  for (int mt = 0; mt < 4; ++mt) {
    Z[mt] = mfma16(Rf[mt][0], zf0, Z[mt]);                     // += R @ Z_old
    Z[mt] = mfma16(Rf[mt][1], zf1, Z[mt]);
  }
}

__global__ __launch_bounds__(64) void scan_local_k(float* ws) {
  const float* u2 = ws + WS_U;
  float* F = ws + WS_F;
  __shared__ short Zl[16 * 72];
  const int lane = threadIdx.x, cq = lane >> 4, cl = lane & 15;
  const int c = blockIdx.x;
  bf16x8 Rf[4][2];
  load_RF(ws + WS_ABAR, Rf, cq, cl);
  f32x4 zero = {0.f, 0.f, 0.f, 0.f};
  f32x4 Z[4], Ub[3][4];
  for (int t = 0; t < 4; ++t) Z[t] = zero;
  const float* ub = u2 + (long)c * LCH * 1024 + cl * 64 + cq * 4;
  for (int t = 0; t < 4; ++t) Ub[0][t] = *(const f32x4*)(ub + t * 16);
  for (int t = 0; t < 4; ++t) Ub[1][t] = *(const f32x4*)(ub + 1024 + t * 16);
#pragma unroll
  for (int ti = 0; ti < LCH; ++ti) {
    const float* un = ub + (ti + 2) * 1024;   // 2-deep prefetch (tail overreads: harmless)
    for (int t = 0; t < 4; ++t) Ub[(ti + 2) % 3][t] = *(const f32x4*)(un + t * 16);
    scan_step(Z, Rf, Zl, Ub[ti % 3], cq, cl);
  }
  for (int t = 0; t < 4; ++t)
    *(f32x4*)&F[(long)c * 1024 + cl * 64 + t * 16 + cq * 4] = Z[t];
}

// boundary redo (<=31 steps with A_L; bitwise-same chain as the old scan_chunks)
// followed by the 64-step final scan writing states bf16.
__global__ __launch_bounds__(64) void scan_final_k(float* ws) {
  const float* u2 = ws + WS_U;
  short* S2bf = (short*)(ws + WS_S);
  __shared__ short Zl[16 * 72];
  const int lane = threadIdx.x, cq = lane >> 4, cl = lane & 15;
  const int c = blockIdx.x;
  bf16x8 Rf[4][2];
  f32x4 zero = {0.f, 0.f, 0.f, 0.f};
  f32x4 Z[4];
  for (int t = 0; t < 4; ++t) Z[t] = zero;

  if (c > 0) {                                  // P_c = scan of F_0..F_{c-1} with A_L
    load_RF(ws + WS_AL, Rf, cq, cl);
    const float* Fb = ws + WS_F;
    f32x4 U[4];
    for (int j = 0; j < c; ++j) {
      const float* fb = Fb + (long)j * 1024 + cl * 64 + cq * 4;
      for (int t = 0; t < 4; ++t) U[t] = *(const f32x4*)(fb + t * 16);
      scan_step(Z, Rf, Zl, U, cq, cl);
    }
  }

  load_RF(ws + WS_ABAR, Rf, cq, cl);
  f32x4 Ub[3][4];
  const float* ub = u2 + (long)c * LCH * 1024 + cl * 64 + cq * 4;
  short* sb = S2bf + (long)c * LCH * 1024 + cl * 64 + cq * 4;
  for (int t = 0; t < 4; ++t) Ub[0][t] = *(const f32x4*)(ub + t * 16);
  for (int t = 0; t < 4; ++t) Ub[1][t] = *(const f32x4*)(ub + 1024 + t * 16);
#pragma unroll
  for (int ti = 0; ti < LCH; ++ti) {
    const float* un = ub + (ti + 2) * 1024;
    for (int t = 0; t < 4; ++t) Ub[(ti + 2) % 3][t] = *(const f32x4*)(un + t * 16);
    scan_step(Z, Rf, Zl, Ub[ti % 3], cq, cl);
    short* so = sb + ti * 1024;
    for (int t = 0; t < 4; ++t) *(u32x2*)(so + t * 16) = packbf4(Z[t]);  // states bf16
  }
}

// ---------------- out_proj: out^T-tiles = C @ states^T + D*x (operand-swapped) ----------
// Per block: 64 bt x 128 h; 4 waves, each 16 bt x 128 h. Loads identical to the
// un-swapped version; D-layout gives each lane 4 CONSECUTIVE h -> pure 16B/lane
// x-reads and out-writes, no LDS, no scalar epilogue.
__global__ __launch_bounds__(256) void out_proj_k(const float* ws, const float* Dv,
                                                  const float* x, float* out) {
  const short* Sbf = (const short*)(ws + WS_S);
  const short* Cbf = (const short*)(ws + WS_CBF);
  const int tid = threadIdx.x;
  const int wid = tid >> 6, lane = tid & 63;
  const int cq = lane >> 4, cl = lane & 15;
  const int bid = blockIdx.x;
  const int bt0 = (bid & 511) * 64 + wid * 16;
  const int h0 = (bid >> 9) * 128;

  const int abt = bt0 + cl;                      // B-operand: n = cl (bt row)
  const int at = abt & (TT - 1), ab = abt >> 11;
  const short* sr = Sbf + (long)(at * 16 + ab) * 64 + cq * 8;
  bf16x8 s0 = *(const bf16x8*)(sr);              // states frags hoisted (reused all h)
  bf16x8 s1 = *(const bf16x8*)(sr + 32);
  const long row = (long)abt * H;

#pragma unroll
  for (int nt = 0; nt < 8; ++nt) {
    const int ht = h0 + nt * 16;
    const short* cr = Cbf + (long)(ht + cl) * 64 + cq * 8;   // A-operand: m = cl -> h
    bf16x8 c0 = *(const bf16x8*)(cr);
    bf16x8 c1 = *(const bf16x8*)(cr + 32);
    f32x4 acc = {0.f, 0.f, 0.f, 0.f};
    acc = mfma16(c0, s0, acc);                   // swapped: D[m=h][n=bt]
    acc = mfma16(c1, s1, acc);
    const long idx = row + ht + cq * 4;          // 4 consecutive h per lane
    f32x4 xv = *(const f32x4*)(x + idx);
    f32x4 dv = *(const f32x4*)(Dv + ht + cq * 4);
    for (int j = 0; j < 4; ++j) acc[j] += dv[j] * xv[j];     // x-path fp32
    *(f32x4*)(out + idx) = acc;
  }
}

extern "C" void kernel_launch(void* const* d_in, const int* in_sizes, int n_in,
                              void* d_out, int out_size, void* d_ws, size_t ws_size,
                              hipStream_t stream) {
  const float* x = (const float*)d_in[0];
  const float* A = (const float*)d_in[1];
  const float* Bm = (const float*)d_in[2];
  const float* Cm = (const float*)d_in[3];
  const float* Dv = (const float*)d_in[4];
  const float* ldt = (const float*)d_in[5];
  float* out = (float*)d_out;
  float* ws = (float*)d_ws;

  k0<<<dim3(66), dim3(256), 0, stream>>>(Bm, Cm, A, ldt, ws);
  k1<<<dim3(512), dim3(256), 0, stream>>>(x, ws);
  scan_local_k<<<dim3(KCH), dim3(64), 0, stream>>>(ws);
  scan_final_k<<<dim3(KCH), dim3(64), 0, stream>>>(ws);
  out_proj_k<<<dim3(4096), dim3(256), 0, stream>>>(ws, Dv, x, out);
}